// Round 3
// baseline (171.618 us; speedup 1.0000x reference)
//
#include <hip/hip_runtime.h>

// Downsample-by-2 along T with depthwise K=8 FIR, reflect pad=3.
// x: (4,64,128,4096) f32 -> 32768 rows of 4096.  y: 32768 rows of 2048.
// y[t] = sum_k w[k] * xp[2t+k],  xp[p] = x[reflect(p-3)]
//
// Direct register version: thread j of a row computes outputs y[8j..8j+7],
// needing x[16j-3 .. 16j+18]  ->  float4 loads A..F = x4[4j-1 .. 4j+4].
// B..E tile the 64B cachelines exactly; A and F re-touch neighbors' lines
// (L1 hits). Reflect edges are built from already-loaded registers.

#define TLEN 4096
#define OLEN 2048
#define NTHREADS 256
#define NROWS 32768

__global__ __launch_bounds__(NTHREADS) void fir_down2_direct(
    const float* __restrict__ x, const float* __restrict__ w,
    float* __restrict__ y)
{
    const int j = threadIdx.x;                         // 0..255
    const long row = blockIdx.x;
    const float4* __restrict__ x4 = (const float4*)(x + row * (long)TLEN);
    float4* __restrict__ y4 = (float4*)(y + row * (long)OLEN);

    const float k0 = w[0], k1 = w[1], k2 = w[2], k3 = w[3];
    const float k4 = w[4], k5 = w[5], k6 = w[6], k7 = w[7];

    const float4 B = x4[4 * j + 0];
    const float4 C = x4[4 * j + 1];
    const float4 D = x4[4 * j + 2];
    const float4 E = x4[4 * j + 3];
    float4 A, F;
    if (j > 0)            A = x4[4 * j - 1];
    else                  A = make_float4(0.f, B.w, B.z, B.y);  // xp[0..2]=x[3],x[2],x[1]
    if (j < NTHREADS - 1) F = x4[4 * j + 4];
    else                  F = make_float4(E.z, E.y, E.x, 0.f);  // xp[4099..4101]=x[4094],x[4093],x[4092]

    // v[m] = x[16j + m - 4], m = 0..23
    const float v[24] = {A.x, A.y, A.z, A.w,  B.x, B.y, B.z, B.w,
                         C.x, C.y, C.z, C.w,  D.x, D.y, D.z, D.w,
                         E.x, E.y, E.z, E.w,  F.x, F.y, F.z, F.w};

    float o[8];
#pragma unroll
    for (int r = 0; r < 8; ++r) {
        // y[8j+r] = sum_k w[k] * x[16j + 2r + k - 3] = sum_k w[k] * v[2r+k+1]
        o[r] = v[2 * r + 1] * k0 + v[2 * r + 2] * k1 + v[2 * r + 3] * k2
             + v[2 * r + 4] * k3 + v[2 * r + 5] * k4 + v[2 * r + 6] * k5
             + v[2 * r + 7] * k6 + v[2 * r + 8] * k7;
    }

    y4[2 * j + 0] = make_float4(o[0], o[1], o[2], o[3]);
    y4[2 * j + 1] = make_float4(o[4], o[5], o[6], o[7]);
}

extern "C" void kernel_launch(void* const* d_in, const int* in_sizes, int n_in,
                              void* d_out, int out_size, void* d_ws, size_t ws_size,
                              hipStream_t stream) {
    const float* x = (const float*)d_in[0];
    const float* w = (const float*)d_in[1];
    float* y = (float*)d_out;
    fir_down2_direct<<<NROWS, NTHREADS, 0, stream>>>(x, w, y);
}

// Round 4
// 131.942 us; speedup vs baseline: 1.3007x; 1.3007x over previous
//
#include <hip/hip_runtime.h>

// Downsample-by-2, depthwise K=8 FIR, reflect pad=3. 32768 rows of 4096 -> 2048.
// Polyphase: E[m]=xp[2m], O[m]=xp[2m+1];
//   y[t] = k0*E[t]+k2*E[t+1]+k4*E[t+2]+k6*E[t+3] + k1*O[t]+k3*O[t+1]+k5*O[t+2]+k7*O[t+3]
// LDS layout: Ebuf[m]=E[m] (16B-aligned base), Obuf[m]=O[m-1] (shifted so the
// interior pair-writes land at even float offsets -> aligned b64 ds_writes).
// Interior: x[4i+1],x[4i+3] -> Ebuf[2i+2..3];  x[4i],x[4i+2] -> Obuf[2i+2..3].
// Reads per 4 outputs: 2x b128 from each array.

#define TLEN 4096
#define OLEN 2048
#define NTHREADS 256
#define NROWS 32768

typedef float f4 __attribute__((ext_vector_type(4)));
typedef float f2 __attribute__((ext_vector_type(2)));

__global__ __launch_bounds__(NTHREADS) void fir_down2_poly(
    const float* __restrict__ x, const float* __restrict__ w,
    float* __restrict__ y)
{
    __shared__ __align__(16) float Ebuf[2052];
    __shared__ __align__(16) float Obuf[2052];

    const int tid = threadIdx.x;
    const long row = blockIdx.x;
    const f4* __restrict__ x4 = (const f4*)(x + row * (long)TLEN);
    f4* __restrict__ y4 = (f4*)(y + row * (long)OLEN);

    const float k0=w[0],k1=w[1],k2=w[2],k3=w[3],k4=w[4],k5=w[5],k6=w[6],k7=w[7];

    // ---- stage (coalesced f4 loads; aligned f2 LDS writes) ----
#pragma unroll
    for (int j = 0; j < 4; ++j) {
        const int i = tid + j * NTHREADS;            // float4 index 0..1023
        const f4 v = __builtin_nontemporal_load(&x4[i]);
        *(f2*)&Ebuf[2*i+2] = (f2){v.y, v.w};         // E[2i+2], E[2i+3]
        *(f2*)&Obuf[2*i+2] = (f2){v.x, v.z};         // O[2i+1], O[2i+2]
        if (i == 0) {            // left reflect from x[0..3]
            Ebuf[0] = v.w;       // E[0]=x[3]
            Ebuf[1] = v.y;       // E[1]=x[1]
            Obuf[1] = v.z;       // O[0]=x[2]
            Obuf[0] = 0.f;
        }
        if (i == 1023) {         // right reflect from x[4092..4095]
            Ebuf[2050] = v.y;    // E[2050]=x[4093]
            Obuf[2050] = v.z;    // O[2049]=x[4094]
            Obuf[2051] = v.x;    // O[2050]=x[4092]
            Ebuf[2051] = 0.f;
        }
    }
    __syncthreads();

    // ---- compute: 2 groups of 4 contiguous outputs per thread ----
    const f4* E4 = (const f4*)Ebuf;
    const f4* O4 = (const f4*)Obuf;
#pragma unroll
    for (int g = 0; g < 2; ++g) {
        const int u = tid + g * NTHREADS;            // 0..511
        const f4 eA = E4[u], eB = E4[u + 1];         // E[4u..4u+7]
        const f4 oA = O4[u], oB = O4[u + 1];         // O[4u-1..4u+6]
        const float Ev[7] = {eA.x, eA.y, eA.z, eA.w, eB.x, eB.y, eB.z};
        const float Ov[7] = {oA.y, oA.z, oA.w, oB.x, oB.y, oB.z, oB.w};
        float o[4];
#pragma unroll
        for (int r = 0; r < 4; ++r)
            o[r] = Ev[r] * k0 + Ov[r] * k1 + Ev[r+1] * k2 + Ov[r+1] * k3
                 + Ev[r+2] * k4 + Ov[r+2] * k5 + Ev[r+3] * k6 + Ov[r+3] * k7;
        const f4 out = {o[0], o[1], o[2], o[3]};
        __builtin_nontemporal_store(out, &y4[u]);
    }
}

extern "C" void kernel_launch(void* const* d_in, const int* in_sizes, int n_in,
                              void* d_out, int out_size, void* d_ws, size_t ws_size,
                              hipStream_t stream) {
    const float* x = (const float*)d_in[0];
    const float* w = (const float*)d_in[1];
    float* y = (float*)d_out;
    fir_down2_poly<<<NROWS, NTHREADS, 0, stream>>>(x, w, y);
}

// Round 5
// 128.638 us; speedup vs baseline: 1.3341x; 1.0257x over previous
//
#include <hip/hip_runtime.h>

// Downsample-by-2, depthwise K=8 FIR, reflect pad=3. 32768 rows of 4096 -> 2048.
// Polyphase (E[m]=xp[2m]=x[2m-3], O[m]=xp[2m+1]=x[2m-2]):
//   y[t] = k0*E[t]+k2*E[t+1]+k4*E[t+2]+k6*E[t+3] + k1*O[t]+k3*O[t+1]+k5*O[t+2]+k7*O[t+3]
// Wave-private version: each wave owns a 1024-float segment of one row, stages
// its own E/O LDS buffers (Ob shifted by 1 so pair-writes are 8B-aligned), and
// syncs with a wave-local lgkmcnt(0) only — NO __syncthreads, no inter-wave
// coupling. Halo = one extra float4 load by lanes 0/63 (L2-hit, +0.8%).

#define TLEN 4096
#define OLEN 2048
#define NTHREADS 256
#define NROWS 32768

typedef float f4 __attribute__((ext_vector_type(4)));
typedef float f2 __attribute__((ext_vector_type(2)));

__global__ __launch_bounds__(NTHREADS) void fir_down2_wavepriv(
    const float* __restrict__ x, const float* __restrict__ w,
    float* __restrict__ y)
{
    // per-wave: Eb[m] = E[512*wv + m], Ob[m] = O[512*wv + m - 1], m in [0,515]
    __shared__ __align__(16) float Eb[4][520];
    __shared__ __align__(16) float Ob[4][520];

    const int tid = threadIdx.x;
    const int wv = tid >> 6;        // wave 0..3 (segment within the row)
    const int lane = tid & 63;
    const long row = blockIdx.x;
    const f4* __restrict__ x4 = (const f4*)(x + row * (long)TLEN);
    f4* __restrict__ y4 = (f4*)(y + row * (long)OLEN) + 128 * wv;

    const float k0=w[0],k1=w[1],k2=w[2],k3=w[3],k4=w[4],k5=w[5],k6=w[6],k7=w[7];

    float* __restrict__ Ew = Eb[wv];
    float* __restrict__ Ow = Ob[wv];

    // ---- stage segment (coalesced f4 loads; aligned f2 LDS writes) ----
    f4 v[4];
#pragma unroll
    for (int j = 0; j < 4; ++j) {
        const int q = 64 * j + lane;                 // local f4 idx 0..255
        v[j] = __builtin_nontemporal_load(&x4[256 * wv + q]);
        *(f2*)&Ew[2*q + 2] = (f2){v[j].y, v[j].w};   // E[.. +2q+2], E[.. +2q+3]
        *(f2*)&Ow[2*q + 2] = (f2){v[j].x, v[j].z};   // O[.. +2q+1], O[.. +2q+2]
    }
    // ---- halo / reflect (one lane each side; Ob[0] unused, left garbage) ----
    if (lane == 0) {
        if (wv == 0) { Ew[0] = v[0].w; Ew[1] = v[0].y; Ow[1] = v[0].z; }   // x[3],x[1],x[2]
        else { const f4 L = x4[256*wv - 1]; Ew[0] = L.y; Ew[1] = L.w; Ow[1] = L.z; }
    }
    if (lane == 63) {
        if (wv == 3) { Ew[514] = v[3].y; Ow[514] = v[3].z; Ow[515] = v[3].x; } // x[4093],x[4094],x[4092]
        else { const f4 R = x4[256*wv + 256]; Ew[514] = R.y; Ow[514] = R.x; Ow[515] = R.z; }
    }
    // wave-local sync: all 64 lanes' ds_writes retire with this wave's counter
    asm volatile("s_waitcnt lgkmcnt(0)" ::: "memory");

    // ---- compute: 2 groups of 4 contiguous outputs per lane ----
    const f4* E4 = (const f4*)Ew;
    const f4* O4 = (const f4*)Ow;
#pragma unroll
    for (int g = 0; g < 2; ++g) {
        const int u = lane + 64 * g;                 // local group 0..127
        const f4 eA = E4[u], eB = E4[u + 1];
        const f4 oA = O4[u], oB = O4[u + 1];
        const float Ev[7] = {eA.x, eA.y, eA.z, eA.w, eB.x, eB.y, eB.z};
        const float Ov[7] = {oA.y, oA.z, oA.w, oB.x, oB.y, oB.z, oB.w};
        float o[4];
#pragma unroll
        for (int r = 0; r < 4; ++r)
            o[r] = Ev[r] * k0 + Ov[r] * k1 + Ev[r+1] * k2 + Ov[r+1] * k3
                 + Ev[r+2] * k4 + Ov[r+2] * k5 + Ev[r+3] * k6 + Ov[r+3] * k7;
        const f4 out = {o[0], o[1], o[2], o[3]};
        __builtin_nontemporal_store(out, &y4[u]);
    }
}

extern "C" void kernel_launch(void* const* d_in, const int* in_sizes, int n_in,
                              void* d_out, int out_size, void* d_ws, size_t ws_size,
                              hipStream_t stream) {
    const float* x = (const float*)d_in[0];
    const float* w = (const float*)d_in[1];
    float* y = (float*)d_out;
    fir_down2_wavepriv<<<NROWS, NTHREADS, 0, stream>>>(x, w, y);
}